// Round 1
// baseline (631.955 us; speedup 1.0000x reference)
//
#include <hip/hip_runtime.h>

#define F_IN 128
#define F_OUT 64

// ---------------- degree kernels ----------------

__global__ __launch_bounds__(256) void init_deg_kernel(float* __restrict__ deg, int N) {
    int i = blockIdx.x * blockDim.x + threadIdx.x;
    if (i < N) deg[i] = 2.0f;  // improved=True self-loop weight
}

__global__ __launch_bounds__(256) void edge_deg_kernel(const int* __restrict__ col,
                                                       const float* __restrict__ ew,
                                                       float* __restrict__ deg, int E) {
    int e = blockIdx.x * blockDim.x + threadIdx.x;
    if (e < E) atomicAdd(&deg[col[e]], ew[e]);
}

__global__ __launch_bounds__(256) void dinv_kernel(float* __restrict__ deg, int N) {
    int i = blockIdx.x * blockDim.x + threadIdx.x;
    if (i < N) {
        float d = deg[i];
        deg[i] = (d > 0.0f) ? rsqrtf(d) : 0.0f;  // in-place: deg becomes dinv
    }
}

// ---------------- fused GEMM + dinv scale ----------------
// y[i,:]   = (x[i,:] @ W) * dinv[i]
// acc[i,:] = 2 * y[i,:]          (self-loop contribution, pre-seeded)
// One wave per row; lane = output column. W staged in LDS (32 KB),
// Wl[k*64+lane] -> bank = lane%32, 2 lanes/bank = conflict-free.
__global__ __launch_bounds__(256) void gemm_scale_kernel(const float* __restrict__ x,
                                                         const float* __restrict__ W,
                                                         const float* __restrict__ dinv,
                                                         float* __restrict__ y,
                                                         float* __restrict__ acc, int N) {
    __shared__ float Wl[F_IN * F_OUT];   // 32 KB
    __shared__ float xs[4][F_IN];        // 2 KB, one row per wave

    const int tid  = threadIdx.x;
    const int w    = tid >> 6;
    const int lane = tid & 63;

    // cooperative W load, float4-coalesced
    for (int i = tid; i < (F_IN * F_OUT) / 4; i += 256)
        ((float4*)Wl)[i] = ((const float4*)W)[i];
    __syncthreads();

    const int rowStep = gridDim.x * 4;
    for (int base = blockIdx.x * 4; base < N; base += rowStep) {
        const int row = base + w;
        const bool live = (row < N);
        if (live)
            ((float2*)xs[w])[lane] = ((const float2*)(x + (size_t)row * F_IN))[lane];
        __syncthreads();

        if (live) {
            // 4 partial accumulators to break the FMA dependency chain
            float s0 = 0.f, s1 = 0.f, s2 = 0.f, s3 = 0.f;
            #pragma unroll
            for (int k = 0; k < F_IN; k += 4) {
                float4 xv = *((const float4*)&xs[w][k]);
                s0 += xv.x * Wl[(k + 0) * F_OUT + lane];
                s1 += xv.y * Wl[(k + 1) * F_OUT + lane];
                s2 += xv.z * Wl[(k + 2) * F_OUT + lane];
                s3 += xv.w * Wl[(k + 3) * F_OUT + lane];
            }
            float sum = (s0 + s1) + (s2 + s3);
            float dv  = dinv[row];
            float yv  = sum * dv;
            y[(size_t)row * F_OUT + lane]   = yv;
            acc[(size_t)row * F_OUT + lane] = 2.0f * yv;  // self-loop seed
        }
        __syncthreads();  // protect xs before next iteration
    }
}

// ---------------- per-edge scatter ----------------
// One wave per edge; lane = feature. acc[col] += ew * y[row]
__global__ __launch_bounds__(256) void scatter_kernel(const int* __restrict__ rowi,
                                                      const int* __restrict__ coli,
                                                      const float* __restrict__ ew,
                                                      const float* __restrict__ y,
                                                      float* __restrict__ acc, int E) {
    const int lane = threadIdx.x & 63;
    const int e = blockIdx.x * 4 + (threadIdx.x >> 6);
    if (e < E) {
        const int r = rowi[e];
        const int c = coli[e];
        const float wgt = ew[e];
        const float v = wgt * y[(size_t)r * F_OUT + lane];
        atomicAdd(&acc[(size_t)c * F_OUT + lane], v);
    }
}

// ---------------- finalize ----------------
// out = dinv * acc + b, written to both tuple halves
__global__ __launch_bounds__(256) void finalize_kernel(const float* __restrict__ acc,
                                                       const float* __restrict__ dinv,
                                                       const float* __restrict__ b,
                                                       float* __restrict__ out, int N) {
    const int gid = blockIdx.x * blockDim.x + threadIdx.x;  // one float4 each
    const int total4 = N * (F_OUT / 4);
    if (gid < total4) {
        const int i  = gid >> 4;        // node
        const int c4 = gid & 15;        // float4 index within 64 features
        float4 a  = ((const float4*)acc)[gid];
        float4 bb = ((const float4*)b)[c4];
        float dv  = dinv[i];
        float4 v;
        v.x = dv * a.x + bb.x;
        v.y = dv * a.y + bb.y;
        v.z = dv * a.z + bb.z;
        v.w = dv * a.w + bb.w;
        ((float4*)out)[gid]          = v;
        ((float4*)out)[gid + total4] = v;
    }
}

extern "C" void kernel_launch(void* const* d_in, const int* in_sizes, int n_in,
                              void* d_out, int out_size, void* d_ws, size_t ws_size,
                              hipStream_t stream) {
    const float* x  = (const float*)d_in[0];
    const int*   ei = (const int*)d_in[1];
    const float* ew = (const float*)d_in[2];
    const float* W  = (const float*)d_in[3];
    const float* b  = (const float*)d_in[4];

    const int N = in_sizes[0] / F_IN;   // 100000
    const int E = in_sizes[2];          // 1600000

    const int* rowi = ei;        // edge_index[0]
    const int* coli = ei + E;    // edge_index[1]
    float* out = (float*)d_out;

    // workspace layout: deg/dinv [N pad], y [N*64], acc [N*64]  (~51.6 MB)
    const int Npad = (N + 63) & ~63;
    float* deg = (float*)d_ws;
    float* y   = deg + Npad;
    float* acc = y + (size_t)N * F_OUT;

    init_deg_kernel<<<(N + 255) / 256, 256, 0, stream>>>(deg, N);
    edge_deg_kernel<<<(E + 255) / 256, 256, 0, stream>>>(coli, ew, deg, E);
    dinv_kernel<<<(N + 255) / 256, 256, 0, stream>>>(deg, N);

    int gemmGrid = (N + 3) / 4;
    if (gemmGrid > 2048) gemmGrid = 2048;
    gemm_scale_kernel<<<gemmGrid, 256, 0, stream>>>(x, W, deg, y, acc, N);

    scatter_kernel<<<(E + 3) / 4, 256, 0, stream>>>(rowi, coli, ew, y, acc, E);

    finalize_kernel<<<(N * (F_OUT / 4) + 255) / 256, 256, 0, stream>>>(acc, deg, b, out, N);
}